// Round 5
// baseline (118.313 us; speedup 1.0000x reference)
//
#include <hip/hip_runtime.h>
#include <hip/hip_bf16.h>
#include <stdint.h>

#define Bn 8
#define Cn 256
#define Hn 56
#define Wn 56
#define HWn 3136
#define NHEADS 8
#define HDIM 32
#define SEQ 392
#define NSTR 8
#define QKV_LD 768
// SCALE * log2(e): K is pre-scaled by this in the qkv-GEMM epilogue so the
// attention softmax can use exp2 with no per-score multiply.
#define KSC (0.17677669529663689f * 1.4426950408889634f)

#if __has_builtin(__builtin_amdgcn_exp2f)
#define EXP2(x) __builtin_amdgcn_exp2f(x)
#else
#define EXP2(x) exp2f(x)
#endif

typedef short short8 __attribute__((ext_vector_type(8)));
typedef float floatx4 __attribute__((ext_vector_type(4)));

__device__ __forceinline__ unsigned short f2bf(float f) {
  union { float f; uint32_t u; } v; v.f = f;
  uint32_t u = v.u;
  u += 0x7fffu + ((u >> 16) & 1u);   // RNE
  return (unsigned short)(u >> 16);
}
__device__ __forceinline__ float bf2f(unsigned short h) {
  union { uint32_t u; float f; } v; v.u = ((uint32_t)h) << 16;
  return v.f;
}
__device__ __forceinline__ uint32_t cvt_pk_bf16(float lo, float hi) {
  uint32_t r;
  asm("v_cvt_pk_bf16_f32 %0, %1, %2" : "=v"(r) : "v"(lo), "v"(hi));
  return r;
}
// async global->LDS, 16B per lane; LDS dest = wave-uniform base + lane*16
__device__ __forceinline__ void gload16(const unsigned short* g, unsigned short* l) {
  __builtin_amdgcn_global_load_lds((const __attribute__((address_space(1))) void*)g,
                                   (__attribute__((address_space(3))) void*)l, 16, 0, 0);
}

// ---------------- convert fp32 -> bf16 (both weight matrices, one launch) ----------------
__global__ __launch_bounds__(256) void k_cvt2(const float* __restrict__ a,
                                              const float* __restrict__ b2,
                                              unsigned short* __restrict__ da,
                                              unsigned short* __restrict__ db) {
  int i = blockIdx.x * 256 + threadIdx.x;   // 65536 float4 slots total
  if (i < 49152) {
    float4 v = ((const float4*)a)[i];
    ushort4 o;
    o.x = f2bf(v.x); o.y = f2bf(v.y); o.z = f2bf(v.z); o.w = f2bf(v.w);
    ((ushort4*)da)[i] = o;
  } else {
    int k = i - 49152;
    float4 v = ((const float4*)b2)[k];
    ushort4 o;
    o.x = f2bf(v.x); o.y = f2bf(v.y); o.z = f2bf(v.z); o.w = f2bf(v.w);
    ((ushort4*)db)[k] = o;
  }
}

// ---------------- x [B][C][HW] f32 -> xt [B][HW][C] bf16 ----------------
__global__ __launch_bounds__(256) void k_trans_x(const float* __restrict__ x,
                                                 unsigned short* __restrict__ xt) {
  __shared__ float tile[32][33];
  int pb = blockIdx.x, cb = blockIdx.y, b = blockIdx.z;
  int t = threadIdx.x;
  int c = t >> 3, p4 = (t & 7) * 4;
  float4 v = *(const float4*)(x + (((size_t)b * Cn + cb * 32 + c) * HWn + pb * 32 + p4));
  tile[c][p4 + 0] = v.x; tile[c][p4 + 1] = v.y; tile[c][p4 + 2] = v.z; tile[c][p4 + 3] = v.w;
  __syncthreads();
  int p = t >> 3, c4 = (t & 7) * 4;
  ushort4 o;
  o.x = f2bf(tile[c4 + 0][p]); o.y = f2bf(tile[c4 + 1][p]);
  o.z = f2bf(tile[c4 + 2][p]); o.w = f2bf(tile[c4 + 3][p]);
  *(ushort4*)(xt + (((size_t)b * HWn + pb * 32 + p) * Cn + cb * 32 + c4)) = o;
}

// ---------------- GEMM: C[M][N] = A[M][K] * Bt[N][K]^T + bias ----------------
// m97-style staging: global_load_lds w16, linear LDS, XOR-swizzle via pre-swizzled
// global source (slot ^= row&7), same XOR on ds_read side.
// EPI 0: bf16 pixel-major out [N][M] (K-channel rows scaled by KSC) + w-major
//        side-copy of q/k heads 4-7 into qkvw[b][pixel_w][256]; EPI 1: f32 [M][N]
template <int EPI>
__global__ __launch_bounds__(256) void k_gemm(const unsigned short* __restrict__ A,
                                              const unsigned short* __restrict__ Bt,
                                              const float* __restrict__ bias,
                                              unsigned short* __restrict__ outB,
                                              float* __restrict__ outF,
                                              unsigned short* __restrict__ qkvw,
                                              int M, int N, int K) {
  __shared__ __align__(16) unsigned short As[128 * 64];
  __shared__ __align__(16) unsigned short Bs[128 * 64];
  int t = threadIdx.x;
  int n0 = blockIdx.x * 128, m0 = blockIdx.y * 128;
  int b = blockIdx.z;
  const unsigned short* Bb = Bt + (size_t)b * N * K;
  int lane = t & 63, w = t >> 6;
  int wr = w >> 1, wc = w & 1;
  int g = lane >> 4, q = lane & 15;
  int srow = w * 32 + (lane >> 3);   // staging row (+ i*8)
  int slot = lane & 7;

  floatx4 z4 = {0.f, 0.f, 0.f, 0.f};
  floatx4 acc[4][4];
#pragma unroll
  for (int i = 0; i < 4; i++)
#pragma unroll
    for (int j = 0; j < 4; j++) acc[i][j] = z4;

  for (int k0 = 0; k0 < K; k0 += 64) {
    __syncthreads();   // previous tile's reads complete before overwrite
#pragma unroll
    for (int i = 0; i < 4; i++) {
      int row = srow + i * 8;
      int cs = slot ^ (row & 7);
      gload16(A + (size_t)(m0 + row) * K + k0 + cs * 8, &As[(w * 32 + i * 8) * 64]);
    }
#pragma unroll
    for (int i = 0; i < 4; i++) {
      int row = srow + i * 8;
      int cs = slot ^ (row & 7);
      int nr = n0 + row;
      if (nr < N)
        gload16(Bb + (size_t)nr * K + k0 + cs * 8, &Bs[(w * 32 + i * 8) * 64]);
    }
    asm volatile("s_waitcnt vmcnt(0)" ::: "memory");
    __syncthreads();
#pragma unroll
    for (int kk = 0; kk < 64; kk += 32) {
      short8 af[4], bfr[4];
#pragma unroll
      for (int i = 0; i < 4; i++) {
        int row = wr * 64 + i * 16 + q;
        af[i] = *(const short8*)&As[row * 64 + ((((kk >> 3) + g) ^ (q & 7)) << 3)];
      }
#pragma unroll
      for (int j = 0; j < 4; j++) {
        int row = wc * 64 + j * 16 + q;
        bfr[j] = *(const short8*)&Bs[row * 64 + ((((kk >> 3) + g) ^ (q & 7)) << 3)];
      }
#pragma unroll
      for (int i = 0; i < 4; i++)
#pragma unroll
        for (int j = 0; j < 4; j++)
          acc[i][j] = __builtin_amdgcn_mfma_f32_16x16x32_bf16(af[i], bfr[j], acc[i][j], 0, 0, 0);
    }
  }

#pragma unroll
  for (int i = 0; i < 4; i++) {
    int ob = m0 + wr * 64 + i * 16 + g * 4;
    float bs0 = bias[ob + 0], bs1 = bias[ob + 1], bs2 = bias[ob + 2], bs3 = bias[ob + 3];
    float sc = 1.0f;
    if (EPI == 0 && ob >= 256 && ob < 512) sc = KSC;   // pre-scale K channels
#pragma unroll
    for (int j = 0; j < 4; j++) {
      int col = n0 + wc * 64 + j * 16 + q;
      if (col < N) {
        if (EPI == 0) {
          ushort4 o;
          o.x = f2bf((acc[i][j][0] + bs0) * sc);
          o.y = f2bf((acc[i][j][1] + bs1) * sc);
          o.z = f2bf((acc[i][j][2] + bs2) * sc);
          o.w = f2bf((acc[i][j][3] + bs3) * sc);
          *(ushort4*)(outB + ((size_t)b * N + col) * M + ob) = o;
          // side-copy q/k of heads 4-7 to w-major pixel order
          int wch = -1;
          if (ob >= 128 && ob < 256) wch = ob - 128;            // q heads 4-7
          else if (ob >= 384 && ob < 512) wch = ob - 384 + 128; // k heads 4-7 (scaled)
          if (wch >= 0) {
            int pw = (col % Wn) * Wn + col / Wn;
            *(ushort4*)(qkvw + ((size_t)b * HWn + pw) * 256 + wch) = o;
          }
        } else {
          float* po = outF + (size_t)b * M * N;
          po[(size_t)(ob + 0) * N + col] = acc[i][j][0] + bs0;
          po[(size_t)(ob + 1) * N + col] = acc[i][j][1] + bs1;
          po[(size_t)(ob + 2) * N + col] = acc[i][j][2] + bs2;
          po[(size_t)(ob + 3) * N + col] = acc[i][j][3] + bs3;
        }
      }
    }
  }
}

// ---------------- depthwise 3x3 on v, output TRANSPOSED: vmt[b][ch][pixel] ----------------
// pass 0: heads 0..3, pixels in h-major order; pass 1: heads 4..7, pixels in w-major order.
__global__ __launch_bounds__(256) void k_dwconv_t(const unsigned short* __restrict__ qkv,
                                                  const float* __restrict__ wdw,
                                                  const float* __restrict__ bdw,
                                                  unsigned short* __restrict__ vmt) {
  __shared__ float wS[1152];
  __shared__ float bS[128];
  __shared__ __align__(16) unsigned short tile[16][140];
  int t = threadIdx.x;
  int pass = blockIdx.y, b = blockIdx.z;
  for (int i = t; i < 1152; i += 256) wS[i] = wdw[pass * 1152 + i];
  if (t < 128) bS[t] = bdw[pass * 128 + t];
  __syncthreads();

  int pi = t >> 4, c8 = (t & 15) * 8;
  int i16 = blockIdx.x * 16 + pi;
  int h, w;
  if (pass == 0) { h = i16 / Wn; w = i16 % Wn; }
  else           { w = i16 / Hn; h = i16 % Hn; }

  const unsigned short* vq = qkv + 512 + pass * 128 + c8;
  float a[8];
  short8 vc = *(const short8*)(vq + ((size_t)b * HWn + h * Wn + w) * QKV_LD);
#pragma unroll
  for (int e = 0; e < 8; e++) a[e] = bf2f((unsigned short)vc[e]) + bS[c8 + e];
#pragma unroll
  for (int ky = 0; ky < 3; ky++) {
    int hh = h + ky - 1;
    if (hh < 0 || hh >= Hn) continue;
#pragma unroll
    for (int kx = 0; kx < 3; kx++) {
      int ww = w + kx - 1;
      if (ww < 0 || ww >= Wn) continue;
      short8 vn = *(const short8*)(vq + ((size_t)b * HWn + hh * Wn + ww) * QKV_LD);
#pragma unroll
      for (int e = 0; e < 8; e++) a[e] += bf2f((unsigned short)vn[e]) * wS[(c8 + e) * 9 + ky * 3 + kx];
    }
  }
  short8 o;
#pragma unroll
  for (int e = 0; e < 8; e++) o[e] = (short)f2bf(a[e]);
  *(short8*)&tile[pi][c8] = o;
  __syncthreads();

  int dd = t >> 1, half = t & 1;
  short8 ov;
#pragma unroll
  for (int k2 = 0; k2 < 8; k2++) ov[k2] = (short)tile[half * 8 + k2][dd];
  *(short8*)(vmt + ((size_t)(b * Cn + pass * 128 + dd)) * HWn + blockIdx.x * 16 + half * 8) = ov;
}

// ---------------- stripe attention ----------------
// grid: (stripe 0..7, b*8+hd 0..63, part 0..1), 256 threads (4 waves)
// h-heads read qkvb (h-major); w-heads read qkvw (w-major) -> both contiguous:
// stripe-seq index i0 maps to linear pixel s*392+i0 in the respective layout.
__global__ __launch_bounds__(256) void k_attn(const unsigned short* __restrict__ qkv,
                                              const unsigned short* __restrict__ qkvw,
                                              const unsigned short* __restrict__ vmt,
                                              unsigned short* __restrict__ aout) {
  __shared__ __align__(16) unsigned short Ks[12288];  // 24 j * 4 g * 16 q granules
  __shared__ __align__(16) unsigned short Vf[12800];  // 50 Gc * 32 d granules (d swizzled)
  __shared__ __align__(16) unsigned short Pf[2048];   // 4 waves * 4 Gl * 16 q granules
  int s = blockIdx.x;
  int hd = blockIdx.y & 7, b = blockIdx.y >> 3;
  int part = blockIdx.z;
  int t = threadIdx.x, lane = t & 63, wv = t >> 6;
  bool wst = (hd >= 4);
  int q = lane & 15, g = lane >> 4;
  int sbase = s * SEQ;

  const unsigned short* base; int ld, qoff, koff;
  if (wst) { base = qkvw + (size_t)b * HWn * 256;    ld = 256;    qoff = (hd - 4) * 32; koff = 128 + (hd - 4) * 32; }
  else     { base = qkv  + (size_t)b * HWn * QKV_LD; ld = QKV_LD; qoff = hd * 32;       koff = 256 + hd * 32; }

  int qb0 = part * 13, qb1 = part ? 25 : 13;

  // ---- Q prefetch: all per-wave Q fragments, issued first ----
  short8 qpre[4];
#pragma unroll
  for (int it = 0; it < 4; it++) {
    int qb = qb0 + wv + it * 4;
    int qi = qb * 16 + q;
    int qil = (qi < SEQ) ? qi : 391;
    qpre[it] = *(const short8*)(base + qoff + (size_t)(sbase + qil) * ld + g * 8);
  }

  // ---- stage K keys 0..383, fragment-major ----
  const unsigned short* kgp = base + koff;
#pragma unroll
  for (int P = 0; P < 6; P++) {
    int key = P * 64 + wv * 16 + q;
    int gg = (t >> 4) & 3;
    short8 kv = *(const short8*)(kgp + (size_t)(sbase + key) * ld + gg * 8);
    *(short8*)&Ks[((((key >> 4) * 4 + gg) * 16) + (key & 15)) * 8] = kv;
  }
  // ---- j=24 K fragment (keys 384..391; 392+ masked later) in regs ----
  short8 kf24;
  {
    int key = 384 + q; if (key > 391) key = 391;
    kf24 = *(const short8*)(kgp + (size_t)(sbase + key) * ld + g * 8);
  }
  // ---- stage V fragment-major with d-swizzle ----
  const unsigned short* vg = vmt + ((size_t)(b * Cn + hd * HDIM)) * HWn + sbase;
  for (int idx = t; idx < 1600; idx += 256) {
    int d = idx / 50, Gc = idx % 50;
    short8 vv = *(const short8*)(vg + (size_t)d * HWn + Gc * 8);
    *(short8*)&Vf[(Gc * 32 + (d ^ (Gc & 7))) * 8] = vv;
  }
  __syncthreads();

  floatx4 z4 = {0.f, 0.f, 0.f, 0.f};
  unsigned short* Pw = &Pf[wv * 512];
  int gh = g >> 1, ge = (g & 1) * 4;

#pragma unroll
  for (int it = 0; it < 4; it++) {
    int qb = qb0 + wv + it * 4;
    if (qb >= qb1) continue;
    int qi = qb * 16 + q;
    int qil = (qi < SEQ) ? qi : 391;
    short8 qf = qpre[it];

    // QK^T (swapped): lane holds S^T[key 4g+r][query q], in log2 units
    floatx4 sacc[25];
#pragma unroll
    for (int j = 0; j < 24; j++) {
      short8 kf = *(const short8*)&Ks[((j * 4 + g) * 16 + q) * 8];
      sacc[j] = __builtin_amdgcn_mfma_f32_16x16x32_bf16(kf, qf, z4, 0, 0, 0);
    }
    sacc[24] = __builtin_amdgcn_mfma_f32_16x16x32_bf16(kf24, qf, z4, 0, 0, 0);
    if (g >= 2) { sacc[24][0] = sacc[24][1] = sacc[24][2] = sacc[24][3] = -3.0e38f; }

    // softmax sans max-subtraction (scores bounded; masked -> exp2 -> 0)
    float sm = 0.f;
#pragma unroll
    for (int j = 0; j < 25; j++) {
      float e0 = EXP2(sacc[j][0]); float e1 = EXP2(sacc[j][1]);
      float e2 = EXP2(sacc[j][2]); float e3 = EXP2(sacc[j][3]);
      sacc[j][0] = e0; sacc[j][1] = e1; sacc[j][2] = e2; sacc[j][3] = e3;
      sm += (e0 + e1) + (e2 + e3);
    }
    sm += __shfl_xor(sm, 16);
    sm += __shfl_xor(sm, 32);
    float rcp = 1.0f / sm;

#define WRITEP(cc) do {                                                        \
    uint2 wA, wB;                                                              \
    wA.x = cvt_pk_bf16(sacc[2*(cc)][0], sacc[2*(cc)][1]);                      \
    wA.y = cvt_pk_bf16(sacc[2*(cc)][2], sacc[2*(cc)][3]);                      \
    if (2*(cc)+1 < 25) {                                                       \
      wB.x = cvt_pk_bf16(sacc[2*(cc)+1][0], sacc[2*(cc)+1][1]);                \
      wB.y = cvt_pk_bf16(sacc[2*(cc)+1][2], sacc[2*(cc)+1][3]);                \
    } else { wB.x = 0u; wB.y = 0u; }                                           \
    *(uint2*)&Pw[(gh * 16 + q) * 8 + ge] = wA;                                 \
    *(uint2*)&Pw[((2 + gh) * 16 + q) * 8 + ge] = wB;                           \
  } while (0)

    // PV: 13 chunks of 32 keys; P round-trips per-wave LDS, pipelined 1 ahead
    floatx4 o0 = z4, o1 = z4;
    WRITEP(0);
#pragma unroll
    for (int ch = 0; ch < 13; ch++) {
      asm volatile("s_waitcnt lgkmcnt(0)" ::: "memory");
      short8 pfr = *(const short8*)&Pw[(g * 16 + q) * 8];
      int Gc = ch * 4 + g; if (Gc > 49) Gc = 49;
      int sw = Gc & 7;
      short8 vf0 = *(const short8*)&Vf[(Gc * 32 + (q ^ sw)) * 8];
      short8 vf1 = *(const short8*)&Vf[(Gc * 32 + 16 + (q ^ sw)) * 8];
      if (ch < 12) {
        switch (ch + 1) {   // keep sacc indices compile-time after unroll
          case 1: WRITEP(1); break;  case 2: WRITEP(2); break;
          case 3: WRITEP(3); break;  case 4: WRITEP(4); break;
          case 5: WRITEP(5); break;  case 6: WRITEP(6); break;
          case 7: WRITEP(7); break;  case 8: WRITEP(8); break;
          case 9: WRITEP(9); break;  case 10: WRITEP(10); break;
          case 11: WRITEP(11); break; case 12: WRITEP(12); break;
        }
      }
      o0 = __builtin_amdgcn_mfma_f32_16x16x32_bf16(vf0, pfr, o0, 0, 0, 0);
      o1 = __builtin_amdgcn_mfma_f32_16x16x32_bf16(vf1, pfr, o1, 0, 0, 0);
    }
#undef WRITEP

    if (qi < SEQ) {
      int pq = wst ? ((qil % Wn) * Wn + s * 7 + qil / Wn) : (sbase + qil);
      size_t ob = ((size_t)b * HWn + pq) * Cn + hd * HDIM;
      ushort4 u0, u1;
      u0.x = f2bf(o0[0] * rcp); u0.y = f2bf(o0[1] * rcp);
      u0.z = f2bf(o0[2] * rcp); u0.w = f2bf(o0[3] * rcp);
      u1.x = f2bf(o1[0] * rcp); u1.y = f2bf(o1[1] * rcp);
      u1.z = f2bf(o1[2] * rcp); u1.w = f2bf(o1[3] * rcp);
      *(ushort4*)(aout + ob + g * 4) = u0;
      *(ushort4*)(aout + ob + 16 + g * 4) = u1;
    }
  }
}

extern "C" void kernel_launch(void* const* d_in, const int* in_sizes, int n_in,
                              void* d_out, int out_size, void* d_ws, size_t ws_size,
                              hipStream_t stream) {
  const float* x     = (const float*)d_in[0];
  const float* wqkv  = (const float*)d_in[1];
  const float* bqkv  = (const float*)d_in[2];
  const float* wdw   = (const float*)d_in[3];
  const float* bdw   = (const float*)d_in[4];
  const float* wproj = (const float*)d_in[5];
  const float* bproj = (const float*)d_in[6];
  float* out = (float*)d_out;

  unsigned short* xt   = (unsigned short*)d_ws;                    // [B][HW][256] bf16
  unsigned short* wqb  = xt + (size_t)Bn * HWn * Cn;               // [768][256]
  unsigned short* wpb  = wqb + 768 * 256;                          // [256][256]
  unsigned short* qkvb = wpb + 256 * 256;                          // [B][HW][768] bf16
  unsigned short* vmt  = qkvb + (size_t)Bn * HWn * QKV_LD;         // [B][256ch][HW] bf16
  unsigned short* aout = vmt + (size_t)Bn * HWn * Cn;              // [B][HW][256] bf16
  unsigned short* qkvw = aout + (size_t)Bn * HWn * Cn;             // [B][HW_wmaj][256] bf16

  k_cvt2<<<dim3(256), 256, 0, stream>>>(wqkv, wproj, wqb, wpb);
  k_trans_x<<<dim3(98, 8, Bn), 256, 0, stream>>>(x, xt);
  k_gemm<0><<<dim3(25, 6, Bn), 256, 0, stream>>>(wqb, xt, bqkv, qkvb, nullptr, qkvw, 768, HWn, 256);
  k_dwconv_t<<<dim3(196, 2, Bn), 256, 0, stream>>>(qkvb, wdw, bdw, vmt);
  k_attn<<<dim3(NSTR, Bn * NHEADS, 2), 256, 0, stream>>>(qkvb, qkvw, vmt, aout);
  k_gemm<1><<<dim3(25, 2, Bn), 256, 0, stream>>>(wpb, aout, bproj, nullptr, out, nullptr, 256, HWn, 256);
}

// Round 6
// 109.578 us; speedup vs baseline: 1.0797x; 1.0797x over previous
//
#include <hip/hip_runtime.h>
#include <hip/hip_bf16.h>
#include <stdint.h>

#define Bn 8
#define Cn 256
#define Hn 56
#define Wn 56
#define HWn 3136
#define NHEADS 8
#define HDIM 32
#define SEQ 392
#define NSTR 8
#define QKV_LD 768
// SCALE * log2(e): K is pre-scaled by this in the qkv-GEMM epilogue so the
// attention softmax can use exp2 with no per-score multiply.
#define KSC (0.17677669529663689f * 1.4426950408889634f)

#if __has_builtin(__builtin_amdgcn_exp2f)
#define EXP2(x) __builtin_amdgcn_exp2f(x)
#else
#define EXP2(x) exp2f(x)
#endif

typedef short short8 __attribute__((ext_vector_type(8)));
typedef float floatx4 __attribute__((ext_vector_type(4)));

__device__ __forceinline__ unsigned short f2bf(float f) {
  union { float f; uint32_t u; } v; v.f = f;
  uint32_t u = v.u;
  u += 0x7fffu + ((u >> 16) & 1u);   // RNE
  return (unsigned short)(u >> 16);
}
__device__ __forceinline__ float bf2f(unsigned short h) {
  union { uint32_t u; float f; } v; v.u = ((uint32_t)h) << 16;
  return v.f;
}
__device__ __forceinline__ uint32_t cvt_pk_bf16(float lo, float hi) {
  uint32_t r;
  asm("v_cvt_pk_bf16_f32 %0, %1, %2" : "=v"(r) : "v"(lo), "v"(hi));
  return r;
}
// async global->LDS, 16B per lane; LDS dest = wave-uniform base + lane*16
__device__ __forceinline__ void gload16(const unsigned short* g, unsigned short* l) {
  __builtin_amdgcn_global_load_lds((const __attribute__((address_space(1))) void*)g,
                                   (__attribute__((address_space(3))) void*)l, 16, 0, 0);
}

// ---------------- convert fp32 -> bf16 (both weight matrices, one launch) ----------------
__global__ __launch_bounds__(256) void k_cvt2(const float* __restrict__ a,
                                              const float* __restrict__ b2,
                                              unsigned short* __restrict__ da,
                                              unsigned short* __restrict__ db) {
  int i = blockIdx.x * 256 + threadIdx.x;   // 65536 float4 slots total
  if (i < 49152) {
    float4 v = ((const float4*)a)[i];
    ushort4 o;
    o.x = f2bf(v.x); o.y = f2bf(v.y); o.z = f2bf(v.z); o.w = f2bf(v.w);
    ((ushort4*)da)[i] = o;
  } else {
    int k = i - 49152;
    float4 v = ((const float4*)b2)[k];
    ushort4 o;
    o.x = f2bf(v.x); o.y = f2bf(v.y); o.z = f2bf(v.z); o.w = f2bf(v.w);
    ((ushort4*)db)[k] = o;
  }
}

// ---------------- x [B][C][HW] f32 -> xt [B][HW][C] bf16 ----------------
__global__ __launch_bounds__(256) void k_trans_x(const float* __restrict__ x,
                                                 unsigned short* __restrict__ xt) {
  __shared__ float tile[32][33];
  int pb = blockIdx.x, cb = blockIdx.y, b = blockIdx.z;
  int t = threadIdx.x;
  int c = t >> 3, p4 = (t & 7) * 4;
  float4 v = *(const float4*)(x + (((size_t)b * Cn + cb * 32 + c) * HWn + pb * 32 + p4));
  tile[c][p4 + 0] = v.x; tile[c][p4 + 1] = v.y; tile[c][p4 + 2] = v.z; tile[c][p4 + 3] = v.w;
  __syncthreads();
  int p = t >> 3, c4 = (t & 7) * 4;
  ushort4 o;
  o.x = f2bf(tile[c4 + 0][p]); o.y = f2bf(tile[c4 + 1][p]);
  o.z = f2bf(tile[c4 + 2][p]); o.w = f2bf(tile[c4 + 3][p]);
  *(ushort4*)(xt + (((size_t)b * HWn + pb * 32 + p) * Cn + cb * 32 + c4)) = o;
}

// ---------------- GEMM: C[M][N] = A[M][K] * Bt[N][K]^T + bias ----------------
// 2-phase double-buffered: stage K-tile t+1 (global_load_lds w16, pre-swizzled
// source slot^row) while computing tile t; one vmcnt(0)+barrier per tile.
// 1D grid with XCD batch-chunk swizzle: chunk = grid/8 -> each XCD owns one
// batch, so its B panel (1.6 MB) + weights stay resident in that XCD's L2.
// EPI 0: bf16 pixel-major out [N][M] (K-channel rows scaled by KSC); EPI 1: f32 [M][N]
template <int EPI>
__global__ __launch_bounds__(256) void k_gemm(const unsigned short* __restrict__ A,
                                              const unsigned short* __restrict__ Bt,
                                              const float* __restrict__ bias,
                                              unsigned short* __restrict__ outB,
                                              float* __restrict__ outF,
                                              int M, int N, int K, int nx, int nper) {
  __shared__ __align__(16) unsigned short As[2][128 * 64];
  __shared__ __align__(16) unsigned short Bs[2][128 * 64];
  int t = threadIdx.x;
  int raw = blockIdx.x;
  int chunk = gridDim.x >> 3;
  int wg = (raw & 7) * chunk + (raw >> 3);     // bijective (grid % 8 == 0)
  int b = wg / nper, r = wg % nper;
  int m0 = (r / nx) * 128, n0 = (r % nx) * 128;
  const unsigned short* Bb = Bt + (size_t)b * N * K;
  int lane = t & 63, w = t >> 6;
  int wr = w >> 1, wc = w & 1;
  int g = lane >> 4, q = lane & 15;
  int srow = w * 32 + (lane >> 3);   // staging row (+ i*8)
  int slot = lane & 7;

  // staging source pointers (k0 added per tile)
  const unsigned short* Ag[4];
  const unsigned short* Bg[4];
  bool bok[4];
  int ldst[4];
#pragma unroll
  for (int i = 0; i < 4; i++) {
    int row = srow + i * 8;
    int cs = slot ^ (row & 7);
    Ag[i] = A + (size_t)(m0 + row) * K + cs * 8;
    int nr = n0 + row;
    bok[i] = (nr < N);
    Bg[i] = Bb + (size_t)(bok[i] ? nr : (N - 1)) * K + cs * 8;
    ldst[i] = (w * 32 + i * 8) * 64;
  }

  floatx4 z4 = {0.f, 0.f, 0.f, 0.f};
  floatx4 acc[4][4];
#pragma unroll
  for (int i = 0; i < 4; i++)
#pragma unroll
    for (int j = 0; j < 4; j++) acc[i][j] = z4;

  // prologue: stage tile 0
#pragma unroll
  for (int i = 0; i < 4; i++) gload16(Ag[i], &As[0][ldst[i]]);
#pragma unroll
  for (int i = 0; i < 4; i++) if (bok[i]) gload16(Bg[i], &Bs[0][ldst[i]]);
  asm volatile("s_waitcnt vmcnt(0)" ::: "memory");
  __syncthreads();

  int cur = 0;
  for (int tt = 0; tt < 4; tt++) {
    if (tt < 3) {   // stage next tile into the other buffer
      int k0 = (tt + 1) * 64;
#pragma unroll
      for (int i = 0; i < 4; i++) gload16(Ag[i] + k0, &As[cur ^ 1][ldst[i]]);
#pragma unroll
      for (int i = 0; i < 4; i++) if (bok[i]) gload16(Bg[i] + k0, &Bs[cur ^ 1][ldst[i]]);
    }
#pragma unroll
    for (int kk = 0; kk < 64; kk += 32) {
      short8 af[4], bfr[4];
#pragma unroll
      for (int i = 0; i < 4; i++) {
        int row = wr * 64 + i * 16 + q;
        af[i] = *(const short8*)&As[cur][row * 64 + ((((kk >> 3) + g) ^ (q & 7)) << 3)];
      }
#pragma unroll
      for (int j = 0; j < 4; j++) {
        int row = wc * 64 + j * 16 + q;
        bfr[j] = *(const short8*)&Bs[cur][row * 64 + ((((kk >> 3) + g) ^ (q & 7)) << 3)];
      }
#pragma unroll
      for (int i = 0; i < 4; i++)
#pragma unroll
        for (int j = 0; j < 4; j++)
          acc[i][j] = __builtin_amdgcn_mfma_f32_16x16x32_bf16(af[i], bfr[j], acc[i][j], 0, 0, 0);
    }
    if (tt < 3) {
      asm volatile("s_waitcnt vmcnt(0)" ::: "memory");
      __syncthreads();
      cur ^= 1;
    }
  }

#pragma unroll
  for (int i = 0; i < 4; i++) {
    int ob = m0 + wr * 64 + i * 16 + g * 4;
    float bs0 = bias[ob + 0], bs1 = bias[ob + 1], bs2 = bias[ob + 2], bs3 = bias[ob + 3];
    float sc = 1.0f;
    if (EPI == 0 && ob >= 256 && ob < 512) sc = KSC;   // pre-scale K channels
#pragma unroll
    for (int j = 0; j < 4; j++) {
      int col = n0 + wc * 64 + j * 16 + q;
      if (col < N) {
        if (EPI == 0) {
          ushort4 o;
          o.x = f2bf((acc[i][j][0] + bs0) * sc);
          o.y = f2bf((acc[i][j][1] + bs1) * sc);
          o.z = f2bf((acc[i][j][2] + bs2) * sc);
          o.w = f2bf((acc[i][j][3] + bs3) * sc);
          *(ushort4*)(outB + ((size_t)b * N + col) * M + ob) = o;
        } else {
          float* po = outF + (size_t)b * M * N;
          po[(size_t)(ob + 0) * N + col] = acc[i][j][0] + bs0;
          po[(size_t)(ob + 1) * N + col] = acc[i][j][1] + bs1;
          po[(size_t)(ob + 2) * N + col] = acc[i][j][2] + bs2;
          po[(size_t)(ob + 3) * N + col] = acc[i][j][3] + bs3;
        }
      }
    }
  }
}

// ---------------- depthwise 3x3 on v, output TRANSPOSED: vmt[b][ch][pixel] ----------------
// pass 0: heads 0..3, pixels in h-major order; pass 1: heads 4..7, pixels in
// w-major order. Pass 1 additionally copies q/k channels of heads 4-7 into
// qkvw[b][pixel_w][256] (contiguous 512B writes per pixel).
__global__ __launch_bounds__(256) void k_dwconv_t(const unsigned short* __restrict__ qkv,
                                                  const float* __restrict__ wdw,
                                                  const float* __restrict__ bdw,
                                                  unsigned short* __restrict__ vmt,
                                                  unsigned short* __restrict__ qkvw) {
  __shared__ float wS[1152];
  __shared__ float bS[128];
  __shared__ __align__(16) unsigned short tile[16][140];
  int t = threadIdx.x;
  int pass = blockIdx.y, b = blockIdx.z;
  for (int i = t; i < 1152; i += 256) wS[i] = wdw[pass * 1152 + i];
  if (t < 128) bS[t] = bdw[pass * 128 + t];

  int pi = t >> 4, c8 = (t & 15) * 8;
  int i16 = blockIdx.x * 16 + pi;
  int h, w;
  if (pass == 0) { h = i16 / Wn; w = i16 % Wn; }
  else           { w = i16 / Hn; h = i16 % Hn; }

  // pass 1: w-major q/k side-copy (pixels of this block, full 256 qkvw chans)
  if (pass == 1) {
    int pi2 = t >> 4, c16 = (t & 15) * 16;
    int ib = blockIdx.x * 16 + pi2;
    int w2 = ib / Hn, h2 = ib % Hn;
    size_t src = ((size_t)b * HWn + h2 * Wn + w2) * QKV_LD;
    int sch = (c16 < 128) ? (128 + c16) : (256 + c16);   // q: 128+, k: 384+
    short8 v0 = *(const short8*)(qkv + src + sch);
    short8 v1 = *(const short8*)(qkv + src + sch + 8);
    unsigned short* dst = qkvw + ((size_t)b * HWn + ib) * 256 + c16;
    *(short8*)dst = v0;
    *(short8*)(dst + 8) = v1;
  }
  __syncthreads();

  const unsigned short* vq = qkv + 512 + pass * 128 + c8;
  float a[8];
  short8 vc = *(const short8*)(vq + ((size_t)b * HWn + h * Wn + w) * QKV_LD);
#pragma unroll
  for (int e = 0; e < 8; e++) a[e] = bf2f((unsigned short)vc[e]) + bS[c8 + e];
#pragma unroll
  for (int ky = 0; ky < 3; ky++) {
    int hh = h + ky - 1;
    if (hh < 0 || hh >= Hn) continue;
#pragma unroll
    for (int kx = 0; kx < 3; kx++) {
      int ww = w + kx - 1;
      if (ww < 0 || ww >= Wn) continue;
      short8 vn = *(const short8*)(vq + ((size_t)b * HWn + hh * Wn + ww) * QKV_LD);
#pragma unroll
      for (int e = 0; e < 8; e++) a[e] += bf2f((unsigned short)vn[e]) * wS[(c8 + e) * 9 + ky * 3 + kx];
    }
  }
  short8 o;
#pragma unroll
  for (int e = 0; e < 8; e++) o[e] = (short)f2bf(a[e]);
  *(short8*)&tile[pi][c8] = o;
  __syncthreads();

  int dd = t >> 1, half = t & 1;
  short8 ov;
#pragma unroll
  for (int k2 = 0; k2 < 8; k2++) ov[k2] = (short)tile[half * 8 + k2][dd];
  *(short8*)(vmt + ((size_t)(b * Cn + pass * 128 + dd)) * HWn + blockIdx.x * 16 + half * 8) = ov;
}

// ---------------- stripe attention ----------------
// grid: (stripe 0..7, b*8+hd 0..63, part 0..1), 256 threads (4 waves)
// h-heads read qkvb (h-major); w-heads read qkvw (w-major) -> both contiguous:
// stripe-seq index i0 maps to linear pixel s*392+i0 in the respective layout.
__global__ __launch_bounds__(256) void k_attn(const unsigned short* __restrict__ qkv,
                                              const unsigned short* __restrict__ qkvw,
                                              const unsigned short* __restrict__ vmt,
                                              unsigned short* __restrict__ aout) {
  __shared__ __align__(16) unsigned short Ks[12288];  // 24 j * 4 g * 16 q granules
  __shared__ __align__(16) unsigned short Vf[12800];  // 50 Gc * 32 d granules (d swizzled)
  __shared__ __align__(16) unsigned short Pf[2048];   // 4 waves * 4 Gl * 16 q granules
  int s = blockIdx.x;
  int hd = blockIdx.y & 7, b = blockIdx.y >> 3;
  int part = blockIdx.z;
  int t = threadIdx.x, lane = t & 63, wv = t >> 6;
  bool wst = (hd >= 4);
  int q = lane & 15, g = lane >> 4;
  int sbase = s * SEQ;

  const unsigned short* base; int ld, qoff, koff;
  if (wst) { base = qkvw + (size_t)b * HWn * 256;    ld = 256;    qoff = (hd - 4) * 32; koff = 128 + (hd - 4) * 32; }
  else     { base = qkv  + (size_t)b * HWn * QKV_LD; ld = QKV_LD; qoff = hd * 32;       koff = 256 + hd * 32; }

  int qb0 = part * 13, qb1 = part ? 25 : 13;

  // ---- Q prefetch: all per-wave Q fragments, issued first ----
  short8 qpre[4];
#pragma unroll
  for (int it = 0; it < 4; it++) {
    int qb = qb0 + wv + it * 4;
    int qi = qb * 16 + q;
    int qil = (qi < SEQ) ? qi : 391;
    qpre[it] = *(const short8*)(base + qoff + (size_t)(sbase + qil) * ld + g * 8);
  }

  // ---- stage K keys 0..383, fragment-major ----
  const unsigned short* kgp = base + koff;
#pragma unroll
  for (int P = 0; P < 6; P++) {
    int key = P * 64 + wv * 16 + q;
    int gg = (t >> 4) & 3;
    short8 kv = *(const short8*)(kgp + (size_t)(sbase + key) * ld + gg * 8);
    *(short8*)&Ks[((((key >> 4) * 4 + gg) * 16) + (key & 15)) * 8] = kv;
  }
  // ---- j=24 K fragment (keys 384..391; 392+ masked later) in regs ----
  short8 kf24;
  {
    int key = 384 + q; if (key > 391) key = 391;
    kf24 = *(const short8*)(kgp + (size_t)(sbase + key) * ld + g * 8);
  }
  // ---- stage V fragment-major with d-swizzle ----
  const unsigned short* vg = vmt + ((size_t)(b * Cn + hd * HDIM)) * HWn + sbase;
  for (int idx = t; idx < 1600; idx += 256) {
    int d = idx / 50, Gc = idx % 50;
    short8 vv = *(const short8*)(vg + (size_t)d * HWn + Gc * 8);
    *(short8*)&Vf[(Gc * 32 + (d ^ (Gc & 7))) * 8] = vv;
  }
  __syncthreads();

  floatx4 z4 = {0.f, 0.f, 0.f, 0.f};
  unsigned short* Pw = &Pf[wv * 512];
  int gh = g >> 1, ge = (g & 1) * 4;

#pragma unroll
  for (int it = 0; it < 4; it++) {
    int qb = qb0 + wv + it * 4;
    if (qb >= qb1) continue;
    int qi = qb * 16 + q;
    int qil = (qi < SEQ) ? qi : 391;
    short8 qf = qpre[it];

    // QK^T (swapped): lane holds S^T[key 4g+r][query q], in log2 units
    floatx4 sacc[25];
#pragma unroll
    for (int j = 0; j < 24; j++) {
      short8 kf = *(const short8*)&Ks[((j * 4 + g) * 16 + q) * 8];
      sacc[j] = __builtin_amdgcn_mfma_f32_16x16x32_bf16(kf, qf, z4, 0, 0, 0);
    }
    sacc[24] = __builtin_amdgcn_mfma_f32_16x16x32_bf16(kf24, qf, z4, 0, 0, 0);
    if (g >= 2) { sacc[24][0] = sacc[24][1] = sacc[24][2] = sacc[24][3] = -3.0e38f; }

    // softmax sans max-subtraction (scores bounded; masked -> exp2 -> 0)
    float sm = 0.f;
#pragma unroll
    for (int j = 0; j < 25; j++) {
      float e0 = EXP2(sacc[j][0]); float e1 = EXP2(sacc[j][1]);
      float e2 = EXP2(sacc[j][2]); float e3 = EXP2(sacc[j][3]);
      sacc[j][0] = e0; sacc[j][1] = e1; sacc[j][2] = e2; sacc[j][3] = e3;
      sm += (e0 + e1) + (e2 + e3);
    }
    sm += __shfl_xor(sm, 16);
    sm += __shfl_xor(sm, 32);
    float rcp = 1.0f / sm;

#define WRITEP(cc) do {                                                        \
    uint2 wA, wB;                                                              \
    wA.x = cvt_pk_bf16(sacc[2*(cc)][0], sacc[2*(cc)][1]);                      \
    wA.y = cvt_pk_bf16(sacc[2*(cc)][2], sacc[2*(cc)][3]);                      \
    if (2*(cc)+1 < 25) {                                                       \
      wB.x = cvt_pk_bf16(sacc[2*(cc)+1][0], sacc[2*(cc)+1][1]);                \
      wB.y = cvt_pk_bf16(sacc[2*(cc)+1][2], sacc[2*(cc)+1][3]);                \
    } else { wB.x = 0u; wB.y = 0u; }                                           \
    *(uint2*)&Pw[(gh * 16 + q) * 8 + ge] = wA;                                 \
    *(uint2*)&Pw[((2 + gh) * 16 + q) * 8 + ge] = wB;                           \
  } while (0)

    // PV: 13 chunks of 32 keys; P round-trips per-wave LDS, pipelined 1 ahead
    floatx4 o0 = z4, o1 = z4;
    WRITEP(0);
#pragma unroll
    for (int ch = 0; ch < 13; ch++) {
      asm volatile("s_waitcnt lgkmcnt(0)" ::: "memory");
      short8 pfr = *(const short8*)&Pw[(g * 16 + q) * 8];
      int Gc = ch * 4 + g; if (Gc > 49) Gc = 49;
      int sw = Gc & 7;
      short8 vf0 = *(const short8*)&Vf[(Gc * 32 + (q ^ sw)) * 8];
      short8 vf1 = *(const short8*)&Vf[(Gc * 32 + 16 + (q ^ sw)) * 8];
      if (ch < 12) {
        switch (ch + 1) {   // keep sacc indices compile-time after unroll
          case 1: WRITEP(1); break;  case 2: WRITEP(2); break;
          case 3: WRITEP(3); break;  case 4: WRITEP(4); break;
          case 5: WRITEP(5); break;  case 6: WRITEP(6); break;
          case 7: WRITEP(7); break;  case 8: WRITEP(8); break;
          case 9: WRITEP(9); break;  case 10: WRITEP(10); break;
          case 11: WRITEP(11); break; case 12: WRITEP(12); break;
        }
      }
      o0 = __builtin_amdgcn_mfma_f32_16x16x32_bf16(vf0, pfr, o0, 0, 0, 0);
      o1 = __builtin_amdgcn_mfma_f32_16x16x32_bf16(vf1, pfr, o1, 0, 0, 0);
    }
#undef WRITEP

    if (qi < SEQ) {
      int pq = wst ? ((qil % Wn) * Wn + s * 7 + qil / Wn) : (sbase + qil);
      size_t ob = ((size_t)b * HWn + pq) * Cn + hd * HDIM;
      ushort4 u0, u1;
      u0.x = f2bf(o0[0] * rcp); u0.y = f2bf(o0[1] * rcp);
      u0.z = f2bf(o0[2] * rcp); u0.w = f2bf(o0[3] * rcp);
      u1.x = f2bf(o1[0] * rcp); u1.y = f2bf(o1[1] * rcp);
      u1.z = f2bf(o1[2] * rcp); u1.w = f2bf(o1[3] * rcp);
      *(ushort4*)(aout + ob + g * 4) = u0;
      *(ushort4*)(aout + ob + 16 + g * 4) = u1;
    }
  }
}

extern "C" void kernel_launch(void* const* d_in, const int* in_sizes, int n_in,
                              void* d_out, int out_size, void* d_ws, size_t ws_size,
                              hipStream_t stream) {
  const float* x     = (const float*)d_in[0];
  const float* wqkv  = (const float*)d_in[1];
  const float* bqkv  = (const float*)d_in[2];
  const float* wdw   = (const float*)d_in[3];
  const float* bdw   = (const float*)d_in[4];
  const float* wproj = (const float*)d_in[5];
  const float* bproj = (const float*)d_in[6];
  float* out = (float*)d_out;

  unsigned short* xt   = (unsigned short*)d_ws;                    // [B][HW][256] bf16
  unsigned short* wqb  = xt + (size_t)Bn * HWn * Cn;               // [768][256]
  unsigned short* wpb  = wqb + 768 * 256;                          // [256][256]
  unsigned short* qkvb = wpb + 256 * 256;                          // [B][HW][768] bf16
  unsigned short* vmt  = qkvb + (size_t)Bn * HWn * QKV_LD;         // [B][256ch][HW] bf16
  unsigned short* aout = vmt + (size_t)Bn * HWn * Cn;              // [B][HW][256] bf16
  unsigned short* qkvw = aout + (size_t)Bn * HWn * Cn;             // [B][HW_wmaj][256] bf16

  k_cvt2<<<dim3(256), 256, 0, stream>>>(wqkv, wproj, wqb, wpb);
  k_trans_x<<<dim3(98, 8, Bn), 256, 0, stream>>>(x, xt);
  k_gemm<0><<<dim3(1200), 256, 0, stream>>>(wqb, xt, bqkv, qkvb, nullptr, 768, HWn, 256, 25, 150);
  k_dwconv_t<<<dim3(196, 2, Bn), 256, 0, stream>>>(qkvb, wdw, bdw, vmt, qkvw);
  k_attn<<<dim3(NSTR, Bn * NHEADS, 2), 256, 0, stream>>>(qkvb, qkvw, vmt, aout);
  k_gemm<1><<<dim3(400), 256, 0, stream>>>(wpb, aout, bproj, nullptr, out, 256, HWn, 256, 25, 50);
}